// Round 1
// baseline (3374.464 us; speedup 1.0000x reference)
//
#include <hip/hip_runtime.h>
#include <hip/hip_bf16.h>

#define U16 unsigned short

typedef __attribute__((ext_vector_type(8))) short bf16x8;
typedef __attribute__((ext_vector_type(4))) float f32x4;

__device__ __forceinline__ float bf2f(U16 h) {
  union { unsigned int u; float f; } v; v.u = ((unsigned int)h) << 16; return v.f;
}
__device__ __forceinline__ U16 f2bf(float f) {
  union { float f; unsigned int u; } v; v.f = f;
  unsigned int u = v.u;
  u = (u + 0x7FFFu + ((u >> 16) & 1u)) >> 16;
  return (U16)u;
}
__device__ __forceinline__ float sigm(float x) { return 1.f / (1.f + __expf(-x)); }
__device__ __forceinline__ float tanh_f(float x) {
  x = fminf(10.f, fmaxf(-10.f, x));
  float e = __expf(2.f * x);
  return (e - 1.f) / (e + 1.f);
}

// ---------------- prep kernels ----------------
__global__ void cast_bf16_k(const float* __restrict__ src, U16* __restrict__ dst, int n4) {
  int i = blockIdx.x * blockDim.x + threadIdx.x;
  if (i >= n4) return;
  float4 v = ((const float4*)src)[i];
  uint2 o;
  o.x = (unsigned)f2bf(v.x) | ((unsigned)f2bf(v.y) << 16);
  o.y = (unsigned)f2bf(v.z) | ((unsigned)f2bf(v.w) << 16);
  ((uint2*)dst)[i] = o;
}

__global__ void bias_comb_k(const float* __restrict__ a, const float* __restrict__ b,
                            const float* __restrict__ c, const float* __restrict__ d,
                            float* __restrict__ o1, float* __restrict__ o2) {
  int i = blockIdx.x * blockDim.x + threadIdx.x;
  if (i < 1024) { o1[i] = a[i] + b[i]; o2[i] = c[i] + d[i]; }
}

// Pack Whh (fp32 [1024][256]) into B-frag-linear bf16: Wp[dir][u][g][kk][lane][8]
// value = Whh[g*256 + u*16 + (lane&15)][kk*32 + (lane>>4)*8 + j]
__global__ void pack_whh_k(const float* __restrict__ Wf, const float* __restrict__ Wb,
                           U16* __restrict__ Wp) {
  int i = blockIdx.x * blockDim.x + threadIdx.x;  // 65536 frag-groups of 8
  if (i >= 65536) return;
  int lane = i & 63;
  int kk = (i >> 6) & 7;
  int g  = (i >> 9) & 3;
  int u  = (i >> 11) & 15;
  int d  = i >> 15;
  const float* W = d ? Wb : Wf;
  const float* src = W + (size_t)(g * 256 + u * 16 + (lane & 15)) * 256 + kk * 32 + (lane >> 4) * 8;
  U16 o[8];
#pragma unroll
  for (int j = 0; j < 8; ++j) o[j] = f2bf(src[j]);
  *(uint4*)(Wp + (size_t)i * 8) = *(uint4*)o;
}

// Cast proj_W with K-permutation matching the scan's packed flat layout:
// dst[n][b*256 + ca*16 + u] = src[n][b*256 + u*16 + ca]
__global__ void cast_pw_perm_k(const float* __restrict__ src, U16* __restrict__ dst) {
  int i = blockIdx.x * blockDim.x + threadIdx.x;  // 4096*2048/8 = 1048576
  if (i >= 1048576) return;
  int kp8 = (i & 255) * 8;
  int n = i >> 8;
  const float* row = src + (size_t)n * 2048;
  U16 o[8];
#pragma unroll
  for (int j = 0; j < 8; ++j) {
    int kp = kp8 + j;
    int b = kp >> 8, x = kp & 255;
    int k = b * 256 + (x & 15) * 16 + (x >> 4);
    o[j] = f2bf(row[k]);
  }
  *(uint4*)(dst + (size_t)n * 2048 + kp8) = *(uint4*)o;
}

// ---------------- GEMM: C[M,N] = A[M,K] * B[N,K]^T (+bias) ----------------
template<bool AF32, bool CF32>
__global__ __launch_bounds__(256) void gemm_bt(
    const void* __restrict__ Av, const U16* __restrict__ Bw,
    void* __restrict__ Cv, int M, int N, int K, const float* __restrict__ bias)
{
  __shared__ __attribute__((aligned(16))) U16 As[8][64][8];
  __shared__ __attribute__((aligned(16))) U16 Bs[8][64][8];
  const int tid = threadIdx.x;
  const int lane = tid & 63, wave = tid >> 6;
  const int wm = wave >> 1, wn = wave & 1;
  const long row0 = (long)blockIdx.y * 128;
  const long col0 = (long)blockIdx.x * 128;

  f32x4 zero = {0.f, 0.f, 0.f, 0.f};
  f32x4 acc[4][4];
#pragma unroll
  for (int mi = 0; mi < 4; ++mi)
#pragma unroll
    for (int ni = 0; ni < 4; ++ni) acc[mi][ni] = zero;

  for (int k0 = 0; k0 < K; k0 += 32) {
    __syncthreads();
    if constexpr (AF32) {
      const float* A = (const float*)Av;
#pragma unroll
      for (int i = 0; i < 4; ++i) {
        int ch = i * 256 + tid;
        int r = ch >> 3, cc = ch & 7;
        const float4 v = *(const float4*)(A + (row0 + r) * (long)K + k0 + cc * 4);
        uint2 o;
        o.x = (unsigned)f2bf(v.x) | ((unsigned)f2bf(v.y) << 16);
        o.y = (unsigned)f2bf(v.z) | ((unsigned)f2bf(v.w) << 16);
        *(uint2*)&As[r >> 4][(cc >> 1) * 16 + (r & 15)][(cc & 1) * 4] = o;
      }
    } else {
      const U16* A = (const U16*)Av;
#pragma unroll
      for (int i = 0; i < 2; ++i) {
        int ch = i * 256 + tid;
        int r = ch >> 2, cc = ch & 3;
        uint4 v = *(const uint4*)(A + (row0 + r) * (long)K + k0 + cc * 8);
        *(uint4*)&As[r >> 4][cc * 16 + (r & 15)][0] = v;
      }
    }
#pragma unroll
    for (int i = 0; i < 2; ++i) {
      int ch = i * 256 + tid;
      int r = ch >> 2, cc = ch & 3;
      uint4 v = *(const uint4*)(Bw + (col0 + r) * (long)K + k0 + cc * 8);
      *(uint4*)&Bs[r >> 4][cc * 16 + (r & 15)][0] = v;
    }
    __syncthreads();
    bf16x8 af[4], bfr[4];
#pragma unroll
    for (int mi = 0; mi < 4; ++mi) af[mi] = *(const bf16x8*)&As[wm * 4 + mi][lane][0];
#pragma unroll
    for (int ni = 0; ni < 4; ++ni) bfr[ni] = *(const bf16x8*)&Bs[wn * 4 + ni][lane][0];
#pragma unroll
    for (int mi = 0; mi < 4; ++mi)
#pragma unroll
      for (int ni = 0; ni < 4; ++ni)
        acc[mi][ni] = __builtin_amdgcn_mfma_f32_16x16x32_bf16(af[mi], bfr[ni], acc[mi][ni], 0, 0, 0);
  }

  const int qa = lane >> 4, ca = lane & 15;
#pragma unroll
  for (int mi = 0; mi < 4; ++mi)
#pragma unroll
    for (int ni = 0; ni < 4; ++ni) {
      long col = col0 + wn * 64 + ni * 16 + ca;
      float bv = bias ? bias[col] : 0.f;
#pragma unroll
      for (int rr = 0; rr < 4; ++rr) {
        long row = row0 + wm * 64 + mi * 16 + qa * 4 + rr;
        float v = acc[mi][ni][rr] + bv;
        if constexpr (CF32) ((float*)Cv)[row * N + col] = v;
        else ((U16*)Cv)[row * N + col] = f2bf(v);
      }
    }
}

// ---------------- bidirectional LSTM scan, barrier-free ----------------
// 256 threads = 4 independent waves; wave owns 16 batch rows. B operands come
// straight from the packed Wp in global (L2-resident, coalesced dwordx4 frags)
// -> no LDS staging, no __syncthreads anywhere. h round-trips via a per-wave
// private LDS slice (lgkmcnt ordering only). Bias is pre-folded into G.
// flat written as packed 16B stores with K-permuted layout (k' = b*256+ca*16+u).
__global__ __launch_bounds__(256, 2) void lstm_scan2(
    const U16* __restrict__ G, const U16* __restrict__ Wp,
    U16* __restrict__ flat)
{
  __shared__ __attribute__((aligned(16))) U16 hbuf[4][8][64][8];  // per-wave slices, 32KB
  const int tid = threadIdx.x;
  const int lane = tid & 63, wave = tid >> 6;
  const int qa = lane >> 4, ca = lane & 15;
  const int dir = blockIdx.y;
  const int row0 = blockIdx.x * 64;
  const U16* Gd = G + (size_t)dir * 67108864u;   // [65536][1024] per dir
  const U16* Wd = Wp + (size_t)dir * 262144u;    // [16][4][8][64][8] per dir

  float cst[16][4];
#pragma unroll
  for (int u = 0; u < 16; ++u)
#pragma unroll
    for (int r = 0; r < 4; ++r) cst[u][r] = 0.f;

  for (int s = 0; s < 4; ++s) {
    const int t = dir ? (3 - s) : s;
    bf16x8 af[8];
    if (s == 0) {
      bf16x8 z = {0, 0, 0, 0, 0, 0, 0, 0};
#pragma unroll
      for (int kk = 0; kk < 8; ++kk) af[kk] = z;
    } else {
#pragma unroll
      for (int kk = 0; kk < 8; ++kk) af[kk] = *(const bf16x8*)&hbuf[wave][kk][lane][0];
    }

    U16 hreg[4][16];
    const size_t gbase = ((size_t)(row0 + wave * 16 + qa * 4) * 4 + t) * 1024;

#pragma unroll
    for (int u = 0; u < 16; ++u) {
      const int unit = u * 16 + ca;
      // G gate pre-activations (bias already folded in by stage-A GEMM)
      U16 gv[4][4];
#pragma unroll
      for (int r = 0; r < 4; ++r) {
        size_t grow = gbase + (size_t)r * 4096;
        gv[r][0] = Gd[grow + unit];
        gv[r][1] = Gd[grow + 256 + unit];
        gv[r][2] = Gd[grow + 512 + unit];
        gv[r][3] = Gd[grow + 768 + unit];
      }
      // h @ Whh^T for this unit tile: B frags direct from L2
      const U16* Wu = Wd + u * 16384;
      f32x4 acc[4];
#pragma unroll
      for (int g = 0; g < 4; ++g) { f32x4 z = {0.f, 0.f, 0.f, 0.f}; acc[g] = z; }
#pragma unroll
      for (int kk = 0; kk < 8; ++kk) {
#pragma unroll
        for (int g = 0; g < 4; ++g) {
          bf16x8 bfr = *(const bf16x8*)(Wu + g * 4096 + kk * 512 + lane * 8);
          acc[g] = __builtin_amdgcn_mfma_f32_16x16x32_bf16(af[kk], bfr, acc[g], 0, 0, 0);
        }
      }
#pragma unroll
      for (int r = 0; r < 4; ++r) {
        float gi = acc[0][r] + bf2f(gv[r][0]);
        float gf = acc[1][r] + bf2f(gv[r][1]);
        float gg = acc[2][r] + bf2f(gv[r][2]);
        float go = acc[3][r] + bf2f(gv[r][3]);
        float c = sigm(gf) * cst[u][r] + sigm(gi) * tanh_f(gg);
        cst[u][r] = c;
        float h = sigm(go) * tanh_f(c);
        U16 hb = f2bf(h);
        hreg[r][u] = hb;
        // h -> A-frag layout for next step (k = unit); wave-private slice
        hbuf[wave][u >> 1][((u & 1) * 2 + (ca >> 3)) * 16 + qa * 4 + r][ca & 7] = hb;
      }
    }

    // packed flat writes: flat[row][t*512 + dir*256 + ca*16 + u], 2x16B per row
#pragma unroll
    for (int r = 0; r < 4; ++r) {
      size_t off = (size_t)(row0 + wave * 16 + qa * 4 + r) * 2048 +
                   (size_t)t * 512 + (size_t)dir * 256 + (size_t)ca * 16;
      *(uint4*)(flat + off)     = *(uint4*)&hreg[r][0];
      *(uint4*)(flat + off + 8) = *(uint4*)&hreg[r][8];
    }
  }
}

// ---------------- LayerNorm + exact GELU + residual ----------------
__global__ __launch_bounds__(256) void ln_gelu_res(
    const float* __restrict__ y, const float* __restrict__ x,
    const float* __restrict__ lg, const float* __restrict__ lb,
    float* __restrict__ out)
{
  const int row = blockIdx.x, tid = threadIdx.x;
  const float4* yr = (const float4*)(y + (size_t)row * 4096);
  const float4* xr = (const float4*)(x + (size_t)row * 4096);
  float4* outr = (float4*)(out + (size_t)row * 4096);
  const float4* g4 = (const float4*)lg;
  const float4* b4 = (const float4*)lb;
  float4 v[4];
  float s1 = 0.f, s2 = 0.f;
#pragma unroll
  for (int j = 0; j < 4; ++j) {
    float4 t = yr[j * 256 + tid];
    v[j] = t;
    s1 += t.x + t.y + t.z + t.w;
    s2 += t.x * t.x + t.y * t.y + t.z * t.z + t.w * t.w;
  }
#pragma unroll
  for (int off = 32; off > 0; off >>= 1) {
    s1 += __shfl_down(s1, off);
    s2 += __shfl_down(s2, off);
  }
  __shared__ float red[8];
  const int wave = tid >> 6, lane = tid & 63;
  if (lane == 0) { red[wave] = s1; red[4 + wave] = s2; }
  __syncthreads();
  s1 = red[0] + red[1] + red[2] + red[3];
  s2 = red[4] + red[5] + red[6] + red[7];
  const float mu = s1 * (1.f / 4096.f);
  const float rstd = rsqrtf(s2 * (1.f / 4096.f) - mu * mu + 1e-5f);
  const float inv_sqrt2 = 0.70710678118654752f;
#pragma unroll
  for (int j = 0; j < 4; ++j) {
    float4 gg = g4[j * 256 + tid], bb = b4[j * 256 + tid], xx = xr[j * 256 + tid];
    float4 o;
    float tval;
    tval = (v[j].x - mu) * rstd * gg.x + bb.x; o.x = xx.x + 0.5f * tval * (1.f + erff(tval * inv_sqrt2));
    tval = (v[j].y - mu) * rstd * gg.y + bb.y; o.y = xx.y + 0.5f * tval * (1.f + erff(tval * inv_sqrt2));
    tval = (v[j].z - mu) * rstd * gg.z + bb.z; o.z = xx.z + 0.5f * tval * (1.f + erff(tval * inv_sqrt2));
    tval = (v[j].w - mu) * rstd * gg.w + bb.w; o.w = xx.w + 0.5f * tval * (1.f + erff(tval * inv_sqrt2));
    outr[j * 256 + tid] = o;
  }
}

// ---------------- host ----------------
extern "C" void kernel_launch(void* const* d_in, const int* in_sizes, int n_in,
                              void* d_out, int out_size, void* d_ws, size_t ws_size,
                              hipStream_t stream) {
  const float* x      = (const float*)d_in[0];
  const float* Wih_f  = (const float*)d_in[1];
  const float* Whh_f  = (const float*)d_in[2];
  const float* bih_f  = (const float*)d_in[3];
  const float* bhh_f  = (const float*)d_in[4];
  const float* Wih_b  = (const float*)d_in[5];
  const float* Whh_b  = (const float*)d_in[6];
  const float* bih_b  = (const float*)d_in[7];
  const float* bhh_b  = (const float*)d_in[8];
  const float* proj_W = (const float*)d_in[9];
  const float* proj_b = (const float*)d_in[10];
  const float* ln_g   = (const float*)d_in[11];
  const float* ln_b   = (const float*)d_in[12];
  float* out = (float*)d_out;

  char* ws = (char*)d_ws;
  // layout (bytes):
  //   [0, 268435456)        G bf16 [2][65536][1024]  -- later reused as y fp32 [16384][4096]
  //   [268435456, 335544320) flat bf16 [16384][2048] (K-permuted layout)
  //   then bf16 weights + packed Whh + combined biases (~21 MB)
  U16*  G    = (U16*)(ws);
  float* y   = (float*)(ws);                       // overlaps G (G dead after scan)
  U16*  flat = (U16*)(ws + 268435456);
  U16*  WihF = (U16*)(ws + 335544320);
  U16*  WihB = WihF + 1048576;
  U16*  Wp   = WihB + 1048576;                     // packed Whh frags [2][16][4][8][64][8]
  U16*  PW   = Wp + 524288;
  float* biasF = (float*)(PW + 8388608);
  float* biasB = biasF + 1024;

  // prep: bf16 casts + packed Whh + combined biases
  cast_bf16_k<<<1024, 256, 0, stream>>>(Wih_f, WihF, 262144);
  cast_bf16_k<<<1024, 256, 0, stream>>>(Wih_b, WihB, 262144);
  pack_whh_k<<<256, 256, 0, stream>>>(Whh_f, Whh_b, Wp);
  cast_pw_perm_k<<<4096, 256, 0, stream>>>(proj_W, PW);
  bias_comb_k<<<4, 256, 0, stream>>>(bih_f, bhh_f, bih_b, bhh_b, biasF, biasB);

  // stage A: G_dir = x_chunks @ Wih_dir^T + (bih+bhh)  (M=65536, N=1024, K=1024)
  dim3 g1(8, 512);
  gemm_bt<true, false><<<g1, 256, 0, stream>>>(x, WihF, G, 65536, 1024, 1024, biasF);
  gemm_bt<true, false><<<g1, 256, 0, stream>>>(x, WihB, G + 67108864, 65536, 1024, 1024, biasB);

  // recurrent scan (both directions), writes flat [16384][2048] bf16 (K-permuted)
  lstm_scan2<<<dim3(256, 2), 256, 0, stream>>>(G, Wp, flat);

  // projection: y = flat @ PW^T + proj_b  (M=16384, N=4096, K=2048, same K-perm both sides)
  dim3 g3(32, 128);
  gemm_bt<false, true><<<g3, 256, 0, stream>>>(flat, PW, y, 16384, 4096, 2048, proj_b);

  // LayerNorm + GELU + residual
  ln_gelu_res<<<16384, 256, 0, stream>>>(y, x, ln_g, ln_b, out);
}

// Round 2
// 2832.674 us; speedup vs baseline: 1.1913x; 1.1913x over previous
//
#include <hip/hip_runtime.h>
#include <hip/hip_bf16.h>

#define U16 unsigned short

typedef __attribute__((ext_vector_type(8))) short bf16x8;
typedef __attribute__((ext_vector_type(4))) float f32x4;
typedef __attribute__((address_space(1))) unsigned int as1_u32;
typedef __attribute__((address_space(3))) unsigned int as3_u32;

__device__ __forceinline__ float bf2f(U16 h) {
  union { unsigned int u; float f; } v; v.u = ((unsigned int)h) << 16; return v.f;
}
__device__ __forceinline__ U16 f2bf(float f) {
  union { float f; unsigned int u; } v; v.f = f;
  unsigned int u = v.u;
  u = (u + 0x7FFFu + ((u >> 16) & 1u)) >> 16;
  return (U16)u;
}
__device__ __forceinline__ float sigm(float x) { return 1.f / (1.f + __expf(-x)); }
__device__ __forceinline__ float tanh_f(float x) {
  x = fminf(10.f, fmaxf(-10.f, x));
  float e = __expf(2.f * x);
  return (e - 1.f) / (e + 1.f);
}

// ---------------- prep kernels ----------------
__global__ void cast_bf16_k(const float* __restrict__ src, U16* __restrict__ dst, int n4) {
  int i = blockIdx.x * blockDim.x + threadIdx.x;
  if (i >= n4) return;
  float4 v = ((const float4*)src)[i];
  uint2 o;
  o.x = (unsigned)f2bf(v.x) | ((unsigned)f2bf(v.y) << 16);
  o.y = (unsigned)f2bf(v.z) | ((unsigned)f2bf(v.w) << 16);
  ((uint2*)dst)[i] = o;
}

__global__ void bias_comb_k(const float* __restrict__ a, const float* __restrict__ b,
                            const float* __restrict__ c, const float* __restrict__ d,
                            float* __restrict__ o1, float* __restrict__ o2) {
  int i = blockIdx.x * blockDim.x + threadIdx.x;
  if (i < 1024) { o1[i] = a[i] + b[i]; o2[i] = c[i] + d[i]; }
}

// Pack Whh (fp32 [1024][256]) into B-frag-linear bf16: Wp[dir][u][g][kk][lane][8]
// value = Whh[g*256 + u*16 + (lane&15)][kk*32 + (lane>>4)*8 + j]
__global__ void pack_whh_k(const float* __restrict__ Wf, const float* __restrict__ Wb,
                           U16* __restrict__ Wp) {
  int i = blockIdx.x * blockDim.x + threadIdx.x;  // 65536 frag-groups of 8
  if (i >= 65536) return;
  int lane = i & 63;
  int kk = (i >> 6) & 7;
  int g  = (i >> 9) & 3;
  int u  = (i >> 11) & 15;
  int d  = i >> 15;
  const float* W = d ? Wb : Wf;
  const float* src = W + (size_t)(g * 256 + u * 16 + (lane & 15)) * 256 + kk * 32 + (lane >> 4) * 8;
  U16 o[8];
#pragma unroll
  for (int j = 0; j < 8; ++j) o[j] = f2bf(src[j]);
  *(uint4*)(Wp + (size_t)i * 8) = *(uint4*)o;
}

// Cast proj_W with K-permutation matching the scan's packed flat layout:
// dst[n][b*256 + ca*16 + u] = src[n][b*256 + u*16 + ca]
__global__ void cast_pw_perm_k(const float* __restrict__ src, U16* __restrict__ dst) {
  int i = blockIdx.x * blockDim.x + threadIdx.x;  // 4096*2048/8 = 1048576
  if (i >= 1048576) return;
  int kp8 = (i & 255) * 8;
  int n = i >> 8;
  const float* row = src + (size_t)n * 2048;
  U16 o[8];
#pragma unroll
  for (int j = 0; j < 8; ++j) {
    int kp = kp8 + j;
    int b = kp >> 8, x = kp & 255;
    int k = b * 256 + (x & 15) * 16 + (x >> 4);
    o[j] = f2bf(row[k]);
  }
  *(uint4*)(dst + (size_t)n * 2048 + kp8) = *(uint4*)o;
}

// ---------------- GEMM: C[M,N] = A[M,K] * B[N,K]^T (+bias) ----------------
// CMODE 1: bf16 store, gate-interleaved G' layout [row][u:16][ca:16][g:4] (N must be 1024)
// CMODE 2: fp32 store + bias
template<bool AF32, int CMODE>
__global__ __launch_bounds__(256) void gemm_bt(
    const void* __restrict__ Av, const U16* __restrict__ Bw,
    void* __restrict__ Cv, int M, int N, int K, const float* __restrict__ bias)
{
  __shared__ __attribute__((aligned(16))) U16 As[8][64][8];
  __shared__ __attribute__((aligned(16))) U16 Bs[8][64][8];
  const int tid = threadIdx.x;
  const int lane = tid & 63, wave = tid >> 6;
  const int wm = wave >> 1, wn = wave & 1;
  const long row0 = (long)blockIdx.y * 128;
  const long col0 = (long)blockIdx.x * 128;

  f32x4 zero = {0.f, 0.f, 0.f, 0.f};
  f32x4 acc[4][4];
#pragma unroll
  for (int mi = 0; mi < 4; ++mi)
#pragma unroll
    for (int ni = 0; ni < 4; ++ni) acc[mi][ni] = zero;

  for (int k0 = 0; k0 < K; k0 += 32) {
    __syncthreads();
    if constexpr (AF32) {
      const float* A = (const float*)Av;
#pragma unroll
      for (int i = 0; i < 4; ++i) {
        int ch = i * 256 + tid;
        int r = ch >> 3, cc = ch & 7;
        const float4 v = *(const float4*)(A + (row0 + r) * (long)K + k0 + cc * 4);
        uint2 o;
        o.x = (unsigned)f2bf(v.x) | ((unsigned)f2bf(v.y) << 16);
        o.y = (unsigned)f2bf(v.z) | ((unsigned)f2bf(v.w) << 16);
        *(uint2*)&As[r >> 4][(cc >> 1) * 16 + (r & 15)][(cc & 1) * 4] = o;
      }
    } else {
      const U16* A = (const U16*)Av;
#pragma unroll
      for (int i = 0; i < 2; ++i) {
        int ch = i * 256 + tid;
        int r = ch >> 2, cc = ch & 3;
        uint4 v = *(const uint4*)(A + (row0 + r) * (long)K + k0 + cc * 8);
        *(uint4*)&As[r >> 4][cc * 16 + (r & 15)][0] = v;
      }
    }
#pragma unroll
    for (int i = 0; i < 2; ++i) {
      int ch = i * 256 + tid;
      int r = ch >> 2, cc = ch & 3;
      uint4 v = *(const uint4*)(Bw + (col0 + r) * (long)K + k0 + cc * 8);
      *(uint4*)&Bs[r >> 4][cc * 16 + (r & 15)][0] = v;
    }
    __syncthreads();
    bf16x8 af[4], bfr[4];
#pragma unroll
    for (int mi = 0; mi < 4; ++mi) af[mi] = *(const bf16x8*)&As[wm * 4 + mi][lane][0];
#pragma unroll
    for (int ni = 0; ni < 4; ++ni) bfr[ni] = *(const bf16x8*)&Bs[wn * 4 + ni][lane][0];
#pragma unroll
    for (int mi = 0; mi < 4; ++mi)
#pragma unroll
      for (int ni = 0; ni < 4; ++ni)
        acc[mi][ni] = __builtin_amdgcn_mfma_f32_16x16x32_bf16(af[mi], bfr[ni], acc[mi][ni], 0, 0, 0);
  }

  const int qa = lane >> 4, ca = lane & 15;
#pragma unroll
  for (int mi = 0; mi < 4; ++mi)
#pragma unroll
    for (int ni = 0; ni < 4; ++ni) {
      long col = col0 + wn * 64 + ni * 16 + ca;
      float bv = bias ? bias[col] : 0.f;
#pragma unroll
      for (int rr = 0; rr < 4; ++rr) {
        long row = row0 + wm * 64 + mi * 16 + qa * 4 + rr;
        float v = acc[mi][ni][rr] + bv;
        if constexpr (CMODE == 2) {
          ((float*)Cv)[row * N + col] = v;
        } else {
          // gate-interleaved: col = g*256 + uu*16 + cn  ->  row*1024 + uu*64 + cn*4 + g
          int g = (int)(col >> 8), uu = (int)((col >> 4) & 15), cn = (int)(col & 15);
          ((U16*)Cv)[row * 1024 + uu * 64 + cn * 4 + g] = f2bf(v);
        }
      }
    }
}

// ---------------- bidirectional LSTM scan, v3 ----------------
// 256 threads (4 waves), 64 batch rows, 1 dir per block. Double-buffered Whh
// staging via global_load_lds from frag-linear Wp (one barrier per phase).
// G' gate-interleaved -> 4 coalesced uint2 loads/phase, prefetched 2 ahead.
// h state packed in scalar uints (hp); h->A-frag exchange reuses the consumed
// Bsl buffer at step boundaries. LDS = 64KB -> 2 blocks/CU.
#define STAGE(buf, ut) do {                                                        \
    const U16* _s = Wd + (size_t)(ut) * 16384 + (size_t)(wave * 64 + lane) * 8;    \
    U16* _d = ((U16*)Bsl) + (size_t)(buf) * 16384 + (size_t)(wave * 64) * 8;       \
    _Pragma("unroll")                                                              \
    for (int _i = 0; _i < 8; ++_i)                                                 \
      __builtin_amdgcn_global_load_lds((as1_u32*)(_s + _i * 2048),                 \
                                       (as3_u32*)(_d + _i * 2048), 16, 0, 0);      \
  } while (0)

#define LOADG(pp, slot) do {                                                       \
    int _p = (pp);                                                                 \
    if (_p < 64) {                                                                 \
      int _u = _p & 15, _s2 = _p >> 4;                                             \
      int _t = dir ? (3 - _s2) : _s2;                                              \
      _Pragma("unroll")                                                            \
      for (int _r = 0; _r < 4; ++_r)                                               \
        slot[_r] = *(const uint2*)(Gd + ((size_t)((rbase + _r) * 4 + _t) * 1024    \
                                         + (unsigned)(_u * 64 + ca * 4)));         \
    }                                                                              \
  } while (0)

__global__ __launch_bounds__(256, 2) void lstm_scan3(
    const U16* __restrict__ Gp, const U16* __restrict__ Wp,
    U16* __restrict__ flat)
{
  __shared__ __attribute__((aligned(16))) U16 Bsl[2][4][8][64][8];  // 64KB dbuf
  const int tid = threadIdx.x;
  const int lane = tid & 63, wave = tid >> 6;
  const int qa = lane >> 4, ca = lane & 15;
  const int dir = blockIdx.y;
  const int row0 = blockIdx.x * 64;
  const U16* Gd = Gp + (size_t)dir * 67108864u;   // G' [65536][1024] per dir
  const U16* Wd = Wp + (size_t)dir * 262144u;     // [16][4][8][64][8] per dir
  const int rbase = row0 + wave * 16 + qa * 4;

  float cst[16][4];
#pragma unroll
  for (int u = 0; u < 16; ++u)
#pragma unroll
    for (int r = 0; r < 4; ++r) cst[u][r] = 0.f;

  unsigned hp[16][2];  // packed h: [u][r>>1], lo16=r even, hi16=r odd

  uint2 gA[4], gB[4];
  STAGE(0, 0);
  LOADG(0, gA);
  LOADG(1, gB);
  __syncthreads();

  bf16x8 af[8];
  {
    bf16x8 z = {0, 0, 0, 0, 0, 0, 0, 0};
#pragma unroll
    for (int kk = 0; kk < 8; ++kk) af[kk] = z;
  }

  int cur = 0;
  for (int s = 0; s < 4; ++s) {
    const int t = dir ? (3 - s) : s;
#pragma unroll
    for (int u = 0; u < 16; ++u) {
      const int p = s * 16 + u;
      // stage next Whh tile into the other buffer
      if (u != 15) { STAGE(cur ^ 1, u + 1); }
      else if (s < 3) { STAGE(cur ^ 1, 0); }

      // unpack this phase's G (loaded 2 phases ago), then refill the slot
      float gvf[4][4];
#pragma unroll
      for (int r = 0; r < 4; ++r) {
        uint2 v = (u & 1) ? gB[r] : gA[r];
        gvf[r][0] = bf2f((U16)(v.x & 0xffffu));
        gvf[r][1] = bf2f((U16)(v.x >> 16));
        gvf[r][2] = bf2f((U16)(v.y & 0xffffu));
        gvf[r][3] = bf2f((U16)(v.y >> 16));
      }
      if (u & 1) { LOADG(p + 2, gB); } else { LOADG(p + 2, gA); }

      // gates = h @ Whh^T : 32 MFMAs from current buffer
      f32x4 acc[4];
#pragma unroll
      for (int g = 0; g < 4; ++g) { f32x4 z = {0.f, 0.f, 0.f, 0.f}; acc[g] = z; }
      const U16* bbase = ((const U16*)Bsl) + (size_t)cur * 16384;
#pragma unroll
      for (int kk = 0; kk < 8; ++kk) {
        const U16* bp = bbase + kk * 512 + lane * 8;
#pragma unroll
        for (int g = 0; g < 4; ++g)
          acc[g] = __builtin_amdgcn_mfma_f32_16x16x32_bf16(
              af[kk], *(const bf16x8*)(bp + g * 4096), acc[g], 0, 0, 0);
      }

      // cell update
#pragma unroll
      for (int r = 0; r < 4; ++r) {
        float gi = acc[0][r] + gvf[r][0];
        float gf = acc[1][r] + gvf[r][1];
        float gg = acc[2][r] + gvf[r][2];
        float go = acc[3][r] + gvf[r][3];
        float c = sigm(gf) * cst[u][r] + sigm(gi) * tanh_f(gg);
        cst[u][r] = c;
        float h = sigm(go) * tanh_f(c);
        U16 hb = f2bf(h);
        if ((r & 1) == 0) hp[u][r >> 1] = (unsigned)hb;
        else hp[u][r >> 1] |= ((unsigned)hb << 16);
      }

      if (u == 15) {
        // flat writes for this step: flat[row][t*512+dir*256+ca*16+u'], 2x16B
#pragma unroll
        for (int r = 0; r < 4; ++r) {
          const int rh = r >> 1, sh = (r & 1) * 16;
          unsigned w0 = ((hp[0][rh] >> sh) & 0xffffu) | (((hp[1][rh] >> sh) & 0xffffu) << 16);
          unsigned w1 = ((hp[2][rh] >> sh) & 0xffffu) | (((hp[3][rh] >> sh) & 0xffffu) << 16);
          unsigned w2 = ((hp[4][rh] >> sh) & 0xffffu) | (((hp[5][rh] >> sh) & 0xffffu) << 16);
          unsigned w3 = ((hp[6][rh] >> sh) & 0xffffu) | (((hp[7][rh] >> sh) & 0xffffu) << 16);
          unsigned w4 = ((hp[8][rh] >> sh) & 0xffffu) | (((hp[9][rh] >> sh) & 0xffffu) << 16);
          unsigned w5 = ((hp[10][rh] >> sh) & 0xffffu) | (((hp[11][rh] >> sh) & 0xffffu) << 16);
          unsigned w6 = ((hp[12][rh] >> sh) & 0xffffu) | (((hp[13][rh] >> sh) & 0xffffu) << 16);
          unsigned w7 = ((hp[14][rh] >> sh) & 0xffffu) | (((hp[15][rh] >> sh) & 0xffffu) << 16);
          size_t off = (size_t)(rbase + r) * 2048 + (size_t)t * 512 + (size_t)dir * 256 + (size_t)ca * 16;
          uint4 o0; o0.x = w0; o0.y = w1; o0.z = w2; o0.w = w3;
          uint4 o1; o1.x = w4; o1.y = w5; o1.z = w6; o1.w = w7;
          *(uint4*)(flat + off) = o0;
          *(uint4*)(flat + off + 8) = o1;
        }
        if (s < 3) {
          __syncthreads();  // all waves done reading Bsl[cur]
          // h -> A-frag exchange in the consumed buffer (wave-private slice)
          U16* hx = ((U16*)Bsl) + (size_t)cur * 16384 + (size_t)wave * 4096;
#pragma unroll
          for (int uu = 0; uu < 16; ++uu) {
#pragma unroll
            for (int r = 0; r < 4; ++r) {
              int ln = ((uu & 1) * 2 + (ca >> 3)) * 16 + qa * 4 + r;
              hx[(uu >> 1) * 512 + ln * 8 + (ca & 7)] =
                  (U16)(hp[uu][r >> 1] >> ((r & 1) * 16));
            }
          }
          asm volatile("s_waitcnt lgkmcnt(0)" ::: "memory");
#pragma unroll
          for (int kk = 0; kk < 8; ++kk)
            af[kk] = *(const bf16x8*)(hx + kk * 512 + lane * 8);
        }
      }
      __syncthreads();  // phase barrier: staged buffer ready, exchange protected
      cur ^= 1;
    }
  }
}

// ---------------- LayerNorm + exact GELU + residual ----------------
__global__ __launch_bounds__(256) void ln_gelu_res(
    const float* __restrict__ y, const float* __restrict__ x,
    const float* __restrict__ lg, const float* __restrict__ lb,
    float* __restrict__ out)
{
  const int row = blockIdx.x, tid = threadIdx.x;
  const float4* yr = (const float4*)(y + (size_t)row * 4096);
  const float4* xr = (const float4*)(x + (size_t)row * 4096);
  float4* outr = (float4*)(out + (size_t)row * 4096);
  const float4* g4 = (const float4*)lg;
  const float4* b4 = (const float4*)lb;
  float4 v[4];
  float s1 = 0.f, s2 = 0.f;
#pragma unroll
  for (int j = 0; j < 4; ++j) {
    float4 t = yr[j * 256 + tid];
    v[j] = t;
    s1 += t.x + t.y + t.z + t.w;
    s2 += t.x * t.x + t.y * t.y + t.z * t.z + t.w * t.w;
  }
#pragma unroll
  for (int off = 32; off > 0; off >>= 1) {
    s1 += __shfl_down(s1, off);
    s2 += __shfl_down(s2, off);
  }
  __shared__ float red[8];
  const int wave = tid >> 6, lane = tid & 63;
  if (lane == 0) { red[wave] = s1; red[4 + wave] = s2; }
  __syncthreads();
  s1 = red[0] + red[1] + red[2] + red[3];
  s2 = red[4] + red[5] + red[6] + red[7];
  const float mu = s1 * (1.f / 4096.f);
  const float rstd = rsqrtf(s2 * (1.f / 4096.f) - mu * mu + 1e-5f);
  const float inv_sqrt2 = 0.70710678118654752f;
#pragma unroll
  for (int j = 0; j < 4; ++j) {
    float4 gg = g4[j * 256 + tid], bb = b4[j * 256 + tid], xx = xr[j * 256 + tid];
    float4 o;
    float tval;
    tval = (v[j].x - mu) * rstd * gg.x + bb.x; o.x = xx.x + 0.5f * tval * (1.f + erff(tval * inv_sqrt2));
    tval = (v[j].y - mu) * rstd * gg.y + bb.y; o.y = xx.y + 0.5f * tval * (1.f + erff(tval * inv_sqrt2));
    tval = (v[j].z - mu) * rstd * gg.z + bb.z; o.z = xx.z + 0.5f * tval * (1.f + erff(tval * inv_sqrt2));
    tval = (v[j].w - mu) * rstd * gg.w + bb.w; o.w = xx.w + 0.5f * tval * (1.f + erff(tval * inv_sqrt2));
    outr[j * 256 + tid] = o;
  }
}

// ---------------- host ----------------
extern "C" void kernel_launch(void* const* d_in, const int* in_sizes, int n_in,
                              void* d_out, int out_size, void* d_ws, size_t ws_size,
                              hipStream_t stream) {
  const float* x      = (const float*)d_in[0];
  const float* Wih_f  = (const float*)d_in[1];
  const float* Whh_f  = (const float*)d_in[2];
  const float* bih_f  = (const float*)d_in[3];
  const float* bhh_f  = (const float*)d_in[4];
  const float* Wih_b  = (const float*)d_in[5];
  const float* Whh_b  = (const float*)d_in[6];
  const float* bih_b  = (const float*)d_in[7];
  const float* bhh_b  = (const float*)d_in[8];
  const float* proj_W = (const float*)d_in[9];
  const float* proj_b = (const float*)d_in[10];
  const float* ln_g   = (const float*)d_in[11];
  const float* ln_b   = (const float*)d_in[12];
  float* out = (float*)d_out;

  char* ws = (char*)d_ws;
  // layout (bytes):
  //   [0, 268435456)        G' bf16 [2][65536][1024] gate-interleaved -- reused as y fp32
  //   [268435456, 335544320) flat bf16 [16384][2048] (K-permuted layout)
  //   then bf16 weights + packed Whh + combined biases (~21 MB)
  U16*  G    = (U16*)(ws);
  float* y   = (float*)(ws);                       // overlaps G (G dead after scan)
  U16*  flat = (U16*)(ws + 268435456);
  U16*  WihF = (U16*)(ws + 335544320);
  U16*  WihB = WihF + 1048576;
  U16*  Wp   = WihB + 1048576;                     // packed Whh frags [2][16][4][8][64][8]
  U16*  PW   = Wp + 524288;
  float* biasF = (float*)(PW + 8388608);
  float* biasB = biasF + 1024;

  // prep
  cast_bf16_k<<<1024, 256, 0, stream>>>(Wih_f, WihF, 262144);
  cast_bf16_k<<<1024, 256, 0, stream>>>(Wih_b, WihB, 262144);
  pack_whh_k<<<256, 256, 0, stream>>>(Whh_f, Whh_b, Wp);
  cast_pw_perm_k<<<4096, 256, 0, stream>>>(proj_W, PW);
  bias_comb_k<<<4, 256, 0, stream>>>(bih_f, bhh_f, bih_b, bhh_b, biasF, biasB);

  // stage A: G'_dir = x_chunks @ Wih_dir^T + (bih+bhh), gate-interleaved store
  dim3 g1(8, 512);
  gemm_bt<true, 1><<<g1, 256, 0, stream>>>(x, WihF, G, 65536, 1024, 1024, biasF);
  gemm_bt<true, 1><<<g1, 256, 0, stream>>>(x, WihB, G + 67108864, 65536, 1024, 1024, biasB);

  // recurrent scan (both directions), writes flat [16384][2048] bf16 (K-permuted)
  lstm_scan3<<<dim3(256, 2), 256, 0, stream>>>(G, Wp, flat);

  // projection: y = flat @ PW^T + proj_b  (M=16384, N=4096, K=2048, same K-perm both sides)
  dim3 g3(32, 128);
  gemm_bt<false, 2><<<g3, 256, 0, stream>>>(flat, PW, y, 16384, 4096, 2048, proj_b);

  // LayerNorm + GELU + residual
  ln_gelu_res<<<16384, 256, 0, stream>>>(y, x, ln_g, ln_b, out);
}